// Round 13
// baseline (273.765 us; speedup 1.0000x reference)
//
#include <hip/hip_runtime.h>
#include <hip/hip_bf16.h>

#define HW 16384
#define CC 192
#define BB 8
#define NHD 4
#define HD 48

typedef __attribute__((ext_vector_type(8))) short  short8;
typedef __attribute__((ext_vector_type(4))) float  f32x4;

static __device__ __forceinline__ unsigned short f2bf(float f) {
  unsigned u = __float_as_uint(f);
  u += 0x7fffu + ((u >> 16) & 1u);          // round-to-nearest-even
  return (unsigned short)(u >> 16);
}
// two fp32 -> packed bf16x2 (compiler emits v_cvt_pk_bf16_f32)
static __device__ __forceinline__ unsigned pk2bf(float lo, float hi) {
  __hip_bfloat162 h = __float22bfloat162_rn(make_float2(lo, hi));
  return *reinterpret_cast<unsigned*>(&h);
}

// lgkm-only barrier: LDS visibility without draining vmcnt (T4).
static __device__ __forceinline__ void ldsbar() {
  asm volatile("" ::: "memory");
  asm volatile("s_waitcnt lgkmcnt(0)" ::: "memory");
  __builtin_amdgcn_s_barrier();
  asm volatile("" ::: "memory");
}

// Staging-buffer swizzle (R13): channel-column XOR with row-quad bits.
// Write: lane owns 4 rows (4p..4p+3) of ONE channel c -> col c^((p&7)<<3).
// XOR bits 3-5 keep 8-channel b128 blocks contiguous and in-range (<192).
#define SWZ3(rowq) ((((rowq) & 7)) << 3)

// XOR swizzle used by proj_fin staging (R10 pattern, dword-index based).
#define SWZ_COL(row, cdw) ((cdw) ^ ((((row) >> 3) & 3) << 2))

// Cast Wq (192x192) and Wk (= Wkv rows 0..191) fp32 -> bf16, contiguous.
__global__ __launch_bounds__(256) void cast_w_kernel(
    const float* __restrict__ Wq, const float* __restrict__ Wkv,
    unsigned short* __restrict__ Wb)
{
  const int i = blockIdx.x * 256 + threadIdx.x;   // 0 .. 2*CC*CC-1
  const float v = (i < CC*CC) ? Wq[i] : Wkv[i - CC*CC];
  Wb[i] = f2bf(v);
}

// ---------------------------------------------------------------------------
// Fused q-proj + k-proj + gram, v5 — CONTIGUOUS-LOAD build (R11 base).
// 512 threads: waves 0-3 = q (head wv&3), 4-7 = k. ONLY the global-load
// shape changed vs R11: each wave loads 128-position batches (2 tiles),
// one instr = 2 channels x 512B contiguous (was 4 x 256B), 24 instrs in
// flight (was 12). LDS/barrier/compute structure identical to R11.
// ---------------------------------------------------------------------------
__global__ __launch_bounds__(512, 2) void qkg_kernel(
    const float* __restrict__ x_q, const float* __restrict__ x_k,
    const unsigned short* __restrict__ wb,   // [2][CC][CC] bf16 (Wq | Wk)
    const float* __restrict__ bq, const float* __restrict__ bkv,
    float* __restrict__ gpart)
{
  const int tid  = threadIdx.x;
  const int lane = tid & 63;
  const int wv   = tid >> 6;          // 0..7
  const int half = wv >> 2;           // 0 = q, 1 = k
  const int hh   = wv & 3;            // head (also weight-row group)
  const int wq   = wv & 3;            // wave index within half
  const int b    = blockIdx.y;
  const int p0   = blockIdx.x * 512;
  const int l15  = lane & 15;
  const int lg   = lane >> 4;
  const int ch2  = lane >> 5;         // which of the 2 channels this lane loads
  const int pl32 = lane & 31;         // 32 position-quads across 128 positions

  __shared__ unsigned short Xsq[64][200];     // 25.6 KB
  __shared__ unsigned short Xsk[64][200];     // 25.6 KB
  __shared__ unsigned short QN[NHD][48][68];  // 26.1 KB
  __shared__ unsigned short KN[NHD][48][68];  // 26.1 KB

  const float* Xsrc = (half ? x_k : x_q) + (size_t)b*CC*HW;
  unsigned short (*Xdst)[200] = half ? Xsk : Xsq;
  unsigned short (*DST)[68]   = half ? KN[hh] : QN[hh];

  const unsigned short* W = wb + (size_t)half*CC*CC;
  const float* bias = half ? bkv : bq;
  float bv[3][4];
  #pragma unroll
  for (int mt = 0; mt < 3; ++mt)
    #pragma unroll
    for (int r = 0; r < 4; ++r)
      bv[mt][r] = bias[hh*48 + mt*16 + lg*4 + r];

  // 2-tile (128-pos) load batch: 24 instrs/wave, each 2 x 512B contiguous.
  f32x4 pre[24];
  auto LOADT = [&](int pbase) {       // pbase = start of 128-pos batch
    #pragma unroll
    for (int i = 0; i < 24; ++i) {
      const int c = wq*48 + 2*i + ch2;
      pre[i] = *(const f32x4*)(Xsrc + (size_t)c*HW + pbase + pl32*4);
    }
  };
  // Write ONE 64-pos tile (sel = which half of the batch) into Xdst.
  // Lanes with (pl32>>4)==sel hold that tile's positions (divergent, no bar).
  auto WRITET = [&](int sel) {
    if ((pl32 >> 4) == sel) {
      const int pq = pl32 & 15;                  // row-quad within tile
      #pragma unroll
      for (int i = 0; i < 24; ++i) {
        const int c  = wq*48 + 2*i + ch2;
        const int cs = c ^ SWZ3(pq);
        const unsigned u0 = pk2bf(pre[i][0], pre[i][1]);
        const unsigned u1 = pk2bf(pre[i][2], pre[i][3]);
        Xdst[pq*4 + 0][cs] = (unsigned short)u0;
        Xdst[pq*4 + 1][cs] = (unsigned short)(u0 >> 16);
        Xdst[pq*4 + 2][cs] = (unsigned short)u1;
        Xdst[pq*4 + 3][cs] = (unsigned short)(u1 >> 16);
      }
    }
  };

  f32x4 gacc[3][3];
  #pragma unroll
  for (int mt = 0; mt < 3; ++mt)
    #pragma unroll
    for (int nt = 0; nt < 3; ++nt)
      gacc[mt][nt] = (f32x4){0.f, 0.f, 0.f, 0.f};

  LOADT(p0);                           // batch 0 (tiles 0,1)
  for (int t = 0; t < 8; ++t) {
    WRITET(t & 1);                     // own tile t -> Xsq/Xsk
    ldsbar();                          // staging visible
    if ((t & 1) && t < 7) LOADT(p0 + (t+1)*64);  // next 2-tile batch in flight

    // ---- PROJ own input (weights per-kk from L2) ----
    f32x4 acc[3][4];
    #pragma unroll
    for (int mt = 0; mt < 3; ++mt)
      #pragma unroll
      for (int nt = 0; nt < 4; ++nt)
        acc[mt][nt] = (f32x4){0.f, 0.f, 0.f, 0.f};

    #pragma unroll
    for (int kk = 0; kk < 6; ++kk) {
      short8 afr[3], bfr[4];
      #pragma unroll
      for (int mt = 0; mt < 3; ++mt)
        afr[mt] = *(const short8*)(W + (size_t)(hh*48 + mt*16 + l15)*CC + kk*32 + lg*8);
      #pragma unroll
      for (int nt = 0; nt < 4; ++nt) {
        const int rowq = (nt*16 + l15) >> 2;     // row-quad of this row
        bfr[nt] = *(const short8*)&Xdst[nt*16 + l15][(kk*32 + lg*8) ^ SWZ3(rowq)];
      }
      #pragma unroll
      for (int mt = 0; mt < 3; ++mt)
        #pragma unroll
        for (int nt = 0; nt < 4; ++nt)
          acc[mt][nt] = __builtin_amdgcn_mfma_f32_16x16x32_bf16(
              afr[mt], bfr[nt], acc[mt][nt], 0, 0, 0);
    }

    #pragma unroll
    for (int nt = 0; nt < 4; ++nt) {
      float v[3][4];
      float ss = 0.f;
      #pragma unroll
      for (int mt = 0; mt < 3; ++mt)
        #pragma unroll
        for (int r = 0; r < 4; ++r) {
          const float x = acc[mt][nt][r] + bv[mt][r];
          v[mt][r] = x;
          ss += x*x;
        }
      ss += __shfl_xor(ss, 16);
      ss += __shfl_xor(ss, 32);
      const float rn = 1.0f / fmaxf(sqrtf(ss), 1e-12f);
      #pragma unroll
      for (int mt = 0; mt < 3; ++mt)
        #pragma unroll
        for (int r = 0; r < 4; ++r)
          DST[mt*16 + lg*4 + r][nt*16 + l15] = f2bf(v[mt][r] * rn);
    }
    ldsbar();                          // QN/KN visible to partner wave

    // ---- gram half: q-wave K-chunk s=0, k-wave s=1 ----
    {
      const int s = half;
      short8 ga[3], gb[3];
      #pragma unroll
      for (int mt = 0; mt < 3; ++mt)
        ga[mt] = *(const short8*)&QN[hh][mt*16 + l15][s*32 + lg*8];
      #pragma unroll
      for (int nt = 0; nt < 3; ++nt)
        gb[nt] = *(const short8*)&KN[hh][nt*16 + l15][s*32 + lg*8];
      #pragma unroll
      for (int mt = 0; mt < 3; ++mt)
        #pragma unroll
        for (int nt = 0; nt < 3; ++nt)
          gacc[mt][nt] = __builtin_amdgcn_mfma_f32_16x16x32_bf16(
              ga[mt], gb[nt], gacc[mt][nt], 0, 0, 0);
    }
    // next iteration's WRITET targets Xsq/Xsk (not QN/KN) and is followed
    // by ldsbar before any QN/KN rewrite -> gram reads are safe.
  }

  // 48x48 gram partial: slot = 2*blockIdx.x + half  (64 slots per (b,h))
  float* G = gpart + ((size_t)(b*NHD + hh)*64 + blockIdx.x*2 + half)*2304;
  #pragma unroll
  for (int mt = 0; mt < 3; ++mt)
    #pragma unroll
    for (int nt = 0; nt < 3; ++nt)
      #pragma unroll
      for (int r = 0; r < 4; ++r)
        G[(mt*16 + lg*4 + r)*HD + nt*16 + l15] = gacc[mt][nt][r];
}

// Final projection (CONTROL — unchanged from R10/R11): out = W3_b@x_k + b3_b.
__global__ __launch_bounds__(256) void proj_fin(
    const float* __restrict__ x_k,
    const unsigned short* __restrict__ w3b,
    const float* __restrict__ b3,
    float* __restrict__ of)
{
  const int tid  = threadIdx.x;
  const int lane = tid & 63;
  const int wv   = tid >> 6;
  const int b    = blockIdx.y;
  const int p0   = blockIdx.x * 256;
  const int l15  = lane & 15;
  const int lg   = lane >> 4;
  const int qd   = tid & 15;

  __shared__ unsigned short Xt[2][64][200];

  const float* X = x_k + (size_t)b*CC*HW;
  const unsigned short* Wb = w3b + (size_t)b*CC*CC;
  const float* bias = b3 + (size_t)b*CC;

  short8 afr[6][3];
  #pragma unroll
  for (int kk = 0; kk < 6; ++kk)
    #pragma unroll
    for (int mt = 0; mt < 3; ++mt)
      afr[kk][mt] = *(const short8*)(Wb + (size_t)(wv*48 + mt*16 + l15)*CC + kk*32 + lg*8);

  float bv[3][4];
  #pragma unroll
  for (int mt = 0; mt < 3; ++mt)
    #pragma unroll
    for (int r = 0; r < 4; ++r)
      bv[mt][r] = bias[wv*48 + mt*16 + lg*4 + r];

  f32x4 pre[12];
  auto LOADT = [&](int pb) {
    #pragma unroll
    for (int i = 0; i < 6; ++i) {
      const int cp = (tid >> 4) + i*16;
      const float* base = X + (size_t)(2*cp)*HW + pb + qd*4;
      pre[2*i]   = *(const f32x4*)(base);
      pre[2*i+1] = *(const f32x4*)(base + HW);
    }
  };
  auto WRITET = [&](int buf) {
    #pragma unroll
    for (int i = 0; i < 6; ++i) {
      const int cp = (tid >> 4) + i*16;
      #pragma unroll
      for (int j = 0; j < 4; ++j) {
        const int row = qd*4 + j;
        *(unsigned*)&Xt[buf][row][2*SWZ_COL(row, cp)] =
            pk2bf(pre[2*i][j], pre[2*i+1][j]);
      }
    }
  };

  float* Ofp = of + (size_t)b*CC*HW;

  auto COMPUTE = [&](int buf, int pb) {
    f32x4 acc[3][4];
    #pragma unroll
    for (int mt = 0; mt < 3; ++mt)
      #pragma unroll
      for (int nt = 0; nt < 4; ++nt)
        acc[mt][nt] = (f32x4){0.f, 0.f, 0.f, 0.f};

    #pragma unroll
    for (int kk = 0; kk < 6; ++kk) {
      short8 bfr[4];
      #pragma unroll
      for (int nt = 0; nt < 4; ++nt) {
        const int lgs = lg ^ ((2*nt + (l15 >> 3)) & 3);   // read-side swizzle
        bfr[nt] = *(const short8*)&Xt[buf][nt*16 + l15][kk*32 + lgs*8];
      }
      #pragma unroll
      for (int mt = 0; mt < 3; ++mt)
        #pragma unroll
        for (int nt = 0; nt < 4; ++nt)
          acc[mt][nt] = __builtin_amdgcn_mfma_f32_16x16x32_bf16(
              afr[kk][mt], bfr[nt], acc[mt][nt], 0, 0, 0);
    }

    #pragma unroll
    for (int nt = 0; nt < 4; ++nt) {
      const int col = pb + nt*16 + l15;
      #pragma unroll
      for (int mt = 0; mt < 3; ++mt)
        #pragma unroll
        for (int r = 0; r < 4; ++r)
          Ofp[(size_t)(wv*48 + mt*16 + lg*4 + r)*HW + col] = acc[mt][nt][r] + bv[mt][r];
    }
  };

  LOADT(p0);
  WRITET(0);
  ldsbar();
  #pragma unroll
  for (int t = 0; t < 4; ++t) {
    if (t < 3) LOADT(p0 + (t+1)*64);
    COMPUTE(t & 1, p0 + t*64);
    if (t < 3) {
      WRITET((t & 1) ^ 1);
      ldsbar();
    }
  }
}

// Per (b,h): reduce 64 gram partials, wave-parallel row softmax, then
// M[b][o][h*48+k] = sum_c Wp[o][h*48+c] * attn[c][k]  (fp32 out).
__global__ __launch_bounds__(256) void attn_m_kernel(
    const float* __restrict__ Gpart,
    const float* __restrict__ Wp,
    const float* __restrict__ temp,
    float* __restrict__ Mf)
{
  __shared__ float att[HD][52];
  const int bh  = blockIdx.x;          // 0..31
  const int b   = bh >> 2, h = bh & 3;
  const int tid = threadIdx.x;
  const float* src = Gpart + (size_t)bh*64*2304;

  #pragma unroll
  for (int i = 0; i < 9; ++i) {
    const int e = tid + i*256;         // 2304 = 9*256
    float s = 0.f;
    #pragma unroll
    for (int k = 0; k < 64; ++k) s += src[(size_t)k*2304 + e];
    att[e/48][e%48] = s;
  }
  __syncthreads();

  const int g = tid >> 2, sl = tid & 3;
  if (g < HD) {
    const float t = temp[h];
    const float scale = 0.1f / (1.0f + expf(-t));   // 0.1*sigmoid(t)
    float* row = att[g];
    float m = -1e30f;
    #pragma unroll
    for (int jj = 0; jj < 12; ++jj) m = fmaxf(m, row[sl + jj*4]);
    m = fmaxf(m, __shfl_xor(m, 1));
    m = fmaxf(m, __shfl_xor(m, 2));
    float ev[12];
    float s = 0.f;
    #pragma unroll
    for (int jj = 0; jj < 12; ++jj) {
      const float e = expf((row[sl + jj*4] - m) * scale);
      ev[jj] = e; s += e;
    }
    s += __shfl_xor(s, 1);
    s += __shfl_xor(s, 2);
    const float inv = 1.0f / s;
    #pragma unroll
    for (int jj = 0; jj < 12; ++jj) row[sl + jj*4] = ev[jj] * inv;
  }
  __syncthreads();

  #pragma unroll
  for (int i = 0; i < 36; ++i) {
    const int idx = tid + i*256;
    const int o = idx / HD, k2 = idx % HD;
    const float* wrow = Wp + (size_t)o*CC + h*HD;
    float s = 0.f;
    #pragma unroll
    for (int c = 0; c < HD; ++c) s += wrow[c] * att[c][k2];
    Mf[(size_t)b*CC*CC + (size_t)o*CC + h*HD + k2] = s;
  }
}

// W3_b = M_b @ Wv (bf16 out), b3_b = M_b @ bv + bp (fp32).
__global__ __launch_bounds__(192) void w3_kernel(
    const float* __restrict__ Mf, const float* __restrict__ Wkv,
    const float* __restrict__ bkv, const float* __restrict__ bp,
    unsigned short* __restrict__ W3b, float* __restrict__ b3)
{
  const int b  = blockIdx.x;
  const int o0 = blockIdx.y * 8;
  const int j  = threadIdx.x;
  const float* M  = Mf + ((size_t)b*CC + o0)*CC;
  const float* Wv = Wkv + (size_t)CC*CC;
  const float* bv = bkv + CC;

  float acc[8]  = {0.f,0.f,0.f,0.f,0.f,0.f,0.f,0.f};
  float bacc[8] = {0.f,0.f,0.f,0.f,0.f,0.f,0.f,0.f};
  #pragma unroll 4
  for (int k = 0; k < CC; ++k) {
    const float w  = Wv[(size_t)k*CC + j];
    const float bk = bv[k];
    #pragma unroll
    for (int r = 0; r < 8; ++r) {
      const float m = M[r*CC + k];
      acc[r]  += m * w;
      bacc[r] += m * bk;
    }
  }
  unsigned short* dst = W3b + ((size_t)b*CC + o0)*CC + j;
  #pragma unroll
  for (int r = 0; r < 8; ++r) dst[(size_t)r*CC] = f2bf(acc[r]);
  if (j < 8) b3[(size_t)b*CC + o0 + j] = bacc[j] + bp[o0 + j];
}

extern "C" void kernel_launch(void* const* d_in, const int* in_sizes, int n_in,
                              void* d_out, int out_size, void* d_ws, size_t ws_size,
                              hipStream_t stream)
{
  (void)in_sizes; (void)n_in; (void)out_size; (void)ws_size;
  const float* x_q  = (const float*)d_in[0];
  const float* x_k  = (const float*)d_in[1];
  const float* Wq   = (const float*)d_in[2];
  const float* bq   = (const float*)d_in[3];
  const float* Wkv  = (const float*)d_in[4];
  const float* bkv  = (const float*)d_in[5];
  const float* Wp   = (const float*)d_in[6];
  const float* bp   = (const float*)d_in[7];
  const float* temp = (const float*)d_in[8];

  char* p = (char*)d_ws;
  float* gpart = (float*)p;                 p += (size_t)BB*NHD*64*2304*sizeof(float);
  float* mf = (float*)p;                    p += (size_t)BB*CC*CC*sizeof(float);
  unsigned short* w3b = (unsigned short*)p; p += (size_t)BB*CC*CC*sizeof(unsigned short);
  float* b3 = (float*)p;                    p += (size_t)BB*CC*sizeof(float);
  unsigned short* wb = (unsigned short*)p;  // 2*CC*CC bf16 (Wq | Wk)

  cast_w_kernel<<<dim3((2*CC*CC)/256), 256, 0, stream>>>(Wq, Wkv, wb);

  // fused q-proj + k-proj + gram (contiguous-load build)
  qkg_kernel<<<dim3(HW/512, BB), 512, 0, stream>>>(
      x_q, x_k, wb, bq, bkv, gpart);

  attn_m_kernel<<<dim3(BB*NHD), 256, 0, stream>>>(gpart, Wp, temp, mf);
  w3_kernel<<<dim3(BB, 24), 192, 0, stream>>>(mf, Wkv, bkv, bp, w3b, b3);

  // final: out = W3_b @ x_k + b3_b
  proj_fin<<<dim3(HW/256, BB), 256, 0, stream>>>(x_k, w3b, b3, (float*)d_out);
}

// Round 14
// 192.028 us; speedup vs baseline: 1.4257x; 1.4257x over previous
//
#include <hip/hip_runtime.h>
#include <hip/hip_bf16.h>

#define HW 16384
#define CC 192
#define BB 8
#define NHD 4
#define HD 48

typedef __attribute__((ext_vector_type(8))) short  short8;
typedef __attribute__((ext_vector_type(4))) float  f32x4;

static __device__ __forceinline__ unsigned short f2bf(float f) {
  unsigned u = __float_as_uint(f);
  u += 0x7fffu + ((u >> 16) & 1u);          // round-to-nearest-even
  return (unsigned short)(u >> 16);
}
// two fp32 -> packed bf16x2 (compiler emits v_cvt_pk_bf16_f32)
static __device__ __forceinline__ unsigned pk2bf(float lo, float hi) {
  __hip_bfloat162 h = __float22bfloat162_rn(make_float2(lo, hi));
  return *reinterpret_cast<unsigned*>(&h);
}

// lgkm-only barrier: LDS visibility without draining vmcnt (T4).
static __device__ __forceinline__ void ldsbar() {
  asm volatile("" ::: "memory");
  asm volatile("s_waitcnt lgkmcnt(0)" ::: "memory");
  __builtin_amdgcn_s_barrier();
  asm volatile("" ::: "memory");
}

// XOR swizzle for staging buffers (row stride 100 dwords): spreads each
// 4-store group over 32 banks (verified R10: conflicts 7.1M -> 2.4M).
#define SWZ_COL(row, cdw) ((cdw) ^ ((((row) >> 3) & 3) << 2))

// Cast Wq (192x192) and Wk (= Wkv rows 0..191) fp32 -> bf16, contiguous.
__global__ __launch_bounds__(256) void cast_w_kernel(
    const float* __restrict__ Wq, const float* __restrict__ Wkv,
    unsigned short* __restrict__ Wb)
{
  const int i = blockIdx.x * 256 + threadIdx.x;   // 0 .. 2*CC*CC-1
  const float v = (i < CC*CC) ? Wq[i] : Wkv[i - CC*CC];
  Wb[i] = f2bf(v);
}

// ---------------------------------------------------------------------------
// Fused q-proj + k-proj + gram (R10 structure + DEPTH-2 load pipeline).
// Per block: 256 positions (4 tiles of 64), wave = head. qn/kn live only in
// LDS; gram partials accumulated in regs across tiles, written once.
// ONLY change vs R10: loads for k(t) AND q(t+1) are both issued before
// PROJ(q) -> 24 loads in flight per wave; compiler's per-use vmcnt(N)
// drains only the older 12 at each WRITET.
// ---------------------------------------------------------------------------
__global__ __launch_bounds__(256, 2) void qkg_kernel(
    const float* __restrict__ x_q, const float* __restrict__ x_k,
    const unsigned short* __restrict__ wb,   // [2][CC][CC] bf16 (Wq | Wk)
    const float* __restrict__ bq, const float* __restrict__ bkv,
    float* __restrict__ gpart)
{
  const int tid  = threadIdx.x;
  const int lane = tid & 63;
  const int wv   = tid >> 6;          // wave = head
  const int b    = blockIdx.y;
  const int p0   = blockIdx.x * 256;
  const int l15  = lane & 15;
  const int lg   = lane >> 4;
  const int qd   = tid & 15;

  __shared__ unsigned short Xs[64][200];      // 25.6 KB, swizzled staging
  __shared__ unsigned short QN[NHD][48][68];  // 26.1 KB
  __shared__ unsigned short KN[NHD][48][68];  // 26.1 KB

  const float* Xq = x_q + (size_t)b*CC*HW;
  const float* Xk = x_k + (size_t)b*CC*HW;

  f32x4 preA[12];                     // q tiles
  f32x4 preB[12];                     // k tiles

  auto LOADT = [&](const float* X, int pb, f32x4* pre) {
    #pragma unroll
    for (int i = 0; i < 6; ++i) {
      const int cp = (tid >> 4) + i*16;
      const float* base = X + (size_t)(2*cp)*HW + pb + qd*4;
      pre[2*i]   = *(const f32x4*)(base);
      pre[2*i+1] = *(const f32x4*)(base + HW);
    }
  };
  auto WRITET = [&](const f32x4* pre) {
    #pragma unroll
    for (int i = 0; i < 6; ++i) {
      const int cp = (tid >> 4) + i*16;
      #pragma unroll
      for (int j = 0; j < 4; ++j) {
        const int row = qd*4 + j;
        *(unsigned*)&Xs[row][2*SWZ_COL(row, cp)] =
            pk2bf(pre[2*i][j], pre[2*i+1][j]);
      }
    }
  };

  // Projection + bias + l2norm; result -> DST[c_local][p_local] (bf16).
  auto PROJ = [&](const unsigned short* W, const float* bias,
                  unsigned short (*DST)[68]) {
    f32x4 acc[3][4];
    #pragma unroll
    for (int mt = 0; mt < 3; ++mt)
      #pragma unroll
      for (int nt = 0; nt < 4; ++nt)
        acc[mt][nt] = (f32x4){0.f, 0.f, 0.f, 0.f};

    #pragma unroll
    for (int kk = 0; kk < 6; ++kk) {
      short8 afr[3], bfr[4];
      #pragma unroll
      for (int mt = 0; mt < 3; ++mt)
        afr[mt] = *(const short8*)(W + (size_t)(wv*48 + mt*16 + l15)*CC + kk*32 + lg*8);
      #pragma unroll
      for (int nt = 0; nt < 4; ++nt) {
        const int lgs = lg ^ ((2*nt + (l15 >> 3)) & 3);   // read-side swizzle
        bfr[nt] = *(const short8*)&Xs[nt*16 + l15][kk*32 + lgs*8];
      }
      #pragma unroll
      for (int mt = 0; mt < 3; ++mt)
        #pragma unroll
        for (int nt = 0; nt < 4; ++nt)
          acc[mt][nt] = __builtin_amdgcn_mfma_f32_16x16x32_bf16(
              afr[mt], bfr[nt], acc[mt][nt], 0, 0, 0);
    }

    #pragma unroll
    for (int nt = 0; nt < 4; ++nt) {
      float v[3][4];
      float ss = 0.f;
      #pragma unroll
      for (int mt = 0; mt < 3; ++mt)
        #pragma unroll
        for (int r = 0; r < 4; ++r) {
          const float x = acc[mt][nt][r] + bias[wv*48 + mt*16 + lg*4 + r];
          v[mt][r] = x;
          ss += x*x;
        }
      ss += __shfl_xor(ss, 16);
      ss += __shfl_xor(ss, 32);
      const float rn = 1.0f / fmaxf(sqrtf(ss), 1e-12f);
      #pragma unroll
      for (int mt = 0; mt < 3; ++mt)
        #pragma unroll
        for (int r = 0; r < 4; ++r)
          DST[mt*16 + lg*4 + r][nt*16 + l15] = f2bf(v[mt][r] * rn);
    }
  };

  f32x4 gacc[3][3];
  #pragma unroll
  for (int mt = 0; mt < 3; ++mt)
    #pragma unroll
    for (int nt = 0; nt < 3; ++nt)
      gacc[mt][nt] = (f32x4){0.f, 0.f, 0.f, 0.f};

  LOADT(Xq, p0, preA);
  for (int t = 0; t < 4; ++t) {
    const int pb = p0 + t*64;
    WRITET(preA);                      // q tile -> Xs (drains preA only)
    ldsbar();
    LOADT(Xk, pb, preB);               // k(t) loads in flight
    if (t < 3) LOADT(Xq, pb + 64, preA);  // q(t+1) too: 24 outstanding
    PROJ(wb, bq, QN[wv]);              // q: MFMA + norm -> QN
    ldsbar();                          // all waves done reading Xs(q)
    WRITET(preB);                      // k tile -> Xs (drains preB only)
    ldsbar();
    PROJ(wb + (size_t)CC*CC, bkv, KN[wv]);  // k: MFMA + norm -> KN
    ldsbar();                          // (uniform barrier count across waves)

    // gram: wave-private (own head's QN/KN only) -> no barrier needed
    #pragma unroll
    for (int s = 0; s < 2; ++s) {
      short8 ga[3], gb[3];
      #pragma unroll
      for (int mt = 0; mt < 3; ++mt)
        ga[mt] = *(const short8*)&QN[wv][mt*16 + l15][s*32 + lg*8];
      #pragma unroll
      for (int nt = 0; nt < 3; ++nt)
        gb[nt] = *(const short8*)&KN[wv][nt*16 + l15][s*32 + lg*8];
      #pragma unroll
      for (int mt = 0; mt < 3; ++mt)
        #pragma unroll
        for (int nt = 0; nt < 3; ++nt)
          gacc[mt][nt] = __builtin_amdgcn_mfma_f32_16x16x32_bf16(
              ga[mt], gb[nt], gacc[mt][nt], 0, 0, 0);
    }
  }

  // write 48x48 gram partial for (b, head=wv), slot = blockIdx.x (0..63)
  float* G = gpart + ((size_t)(b*NHD + wv)*64 + blockIdx.x)*2304;
  #pragma unroll
  for (int mt = 0; mt < 3; ++mt)
    #pragma unroll
    for (int nt = 0; nt < 3; ++nt)
      #pragma unroll
      for (int r = 0; r < 4; ++r)
        G[(mt*16 + lg*4 + r)*HD + nt*16 + l15] = gacc[mt][nt][r];
}

// Final projection (CONTROL — unchanged): out = W3_b @ x_k + b3_b.
__global__ __launch_bounds__(256) void proj_fin(
    const float* __restrict__ x_k,
    const unsigned short* __restrict__ w3b,
    const float* __restrict__ b3,
    float* __restrict__ of)
{
  const int tid  = threadIdx.x;
  const int lane = tid & 63;
  const int wv   = tid >> 6;
  const int b    = blockIdx.y;
  const int p0   = blockIdx.x * 256;
  const int l15  = lane & 15;
  const int lg   = lane >> 4;
  const int qd   = tid & 15;

  __shared__ unsigned short Xt[2][64][200];

  const float* X = x_k + (size_t)b*CC*HW;
  const unsigned short* Wb = w3b + (size_t)b*CC*CC;
  const float* bias = b3 + (size_t)b*CC;

  short8 afr[6][3];
  #pragma unroll
  for (int kk = 0; kk < 6; ++kk)
    #pragma unroll
    for (int mt = 0; mt < 3; ++mt)
      afr[kk][mt] = *(const short8*)(Wb + (size_t)(wv*48 + mt*16 + l15)*CC + kk*32 + lg*8);

  float bv[3][4];
  #pragma unroll
  for (int mt = 0; mt < 3; ++mt)
    #pragma unroll
    for (int r = 0; r < 4; ++r)
      bv[mt][r] = bias[wv*48 + mt*16 + lg*4 + r];

  f32x4 pre[12];
  auto LOADT = [&](int pb) {
    #pragma unroll
    for (int i = 0; i < 6; ++i) {
      const int cp = (tid >> 4) + i*16;
      const float* base = X + (size_t)(2*cp)*HW + pb + qd*4;
      pre[2*i]   = *(const f32x4*)(base);
      pre[2*i+1] = *(const f32x4*)(base + HW);
    }
  };
  auto WRITET = [&](int buf) {
    #pragma unroll
    for (int i = 0; i < 6; ++i) {
      const int cp = (tid >> 4) + i*16;
      #pragma unroll
      for (int j = 0; j < 4; ++j) {
        const int row = qd*4 + j;
        *(unsigned*)&Xt[buf][row][2*SWZ_COL(row, cp)] =
            pk2bf(pre[2*i][j], pre[2*i+1][j]);
      }
    }
  };

  float* Ofp = of + (size_t)b*CC*HW;

  auto COMPUTE = [&](int buf, int pb) {
    f32x4 acc[3][4];
    #pragma unroll
    for (int mt = 0; mt < 3; ++mt)
      #pragma unroll
      for (int nt = 0; nt < 4; ++nt)
        acc[mt][nt] = (f32x4){0.f, 0.f, 0.f, 0.f};

    #pragma unroll
    for (int kk = 0; kk < 6; ++kk) {
      short8 bfr[4];
      #pragma unroll
      for (int nt = 0; nt < 4; ++nt) {
        const int lgs = lg ^ ((2*nt + (l15 >> 3)) & 3);   // read-side swizzle
        bfr[nt] = *(const short8*)&Xt[buf][nt*16 + l15][kk*32 + lgs*8];
      }
      #pragma unroll
      for (int mt = 0; mt < 3; ++mt)
        #pragma unroll
        for (int nt = 0; nt < 4; ++nt)
          acc[mt][nt] = __builtin_amdgcn_mfma_f32_16x16x32_bf16(
              afr[kk][mt], bfr[nt], acc[mt][nt], 0, 0, 0);
    }

    #pragma unroll
    for (int nt = 0; nt < 4; ++nt) {
      const int col = pb + nt*16 + l15;
      #pragma unroll
      for (int mt = 0; mt < 3; ++mt)
        #pragma unroll
        for (int r = 0; r < 4; ++r)
          Ofp[(size_t)(wv*48 + mt*16 + lg*4 + r)*HW + col] = acc[mt][nt][r] + bv[mt][r];
    }
  };

  LOADT(p0);
  WRITET(0);
  ldsbar();
  #pragma unroll
  for (int t = 0; t < 4; ++t) {
    if (t < 3) LOADT(p0 + (t+1)*64);
    COMPUTE(t & 1, p0 + t*64);
    if (t < 3) {
      WRITET((t & 1) ^ 1);
      ldsbar();
    }
  }
}

// Per (b,h): reduce 64 gram partials, wave-parallel row softmax, then
// M[b][o][h*48+k] = sum_c Wp[o][h*48+c] * attn[c][k]  (fp32 out).
__global__ __launch_bounds__(256) void attn_m_kernel(
    const float* __restrict__ Gpart,
    const float* __restrict__ Wp,
    const float* __restrict__ temp,
    float* __restrict__ Mf)
{
  __shared__ float att[HD][52];
  const int bh  = blockIdx.x;          // 0..31
  const int b   = bh >> 2, h = bh & 3;
  const int tid = threadIdx.x;
  const float* src = Gpart + (size_t)bh*64*2304;

  #pragma unroll
  for (int i = 0; i < 9; ++i) {
    const int e = tid + i*256;         // 2304 = 9*256
    float s = 0.f;
    #pragma unroll
    for (int k = 0; k < 64; ++k) s += src[(size_t)k*2304 + e];
    att[e/48][e%48] = s;
  }
  __syncthreads();

  const int g = tid >> 2, sl = tid & 3;
  if (g < HD) {
    const float t = temp[h];
    const float scale = 0.1f / (1.0f + expf(-t));   // 0.1*sigmoid(t)
    float* row = att[g];
    float m = -1e30f;
    #pragma unroll
    for (int jj = 0; jj < 12; ++jj) m = fmaxf(m, row[sl + jj*4]);
    m = fmaxf(m, __shfl_xor(m, 1));
    m = fmaxf(m, __shfl_xor(m, 2));
    float ev[12];
    float s = 0.f;
    #pragma unroll
    for (int jj = 0; jj < 12; ++jj) {
      const float e = expf((row[sl + jj*4] - m) * scale);
      ev[jj] = e; s += e;
    }
    s += __shfl_xor(s, 1);
    s += __shfl_xor(s, 2);
    const float inv = 1.0f / s;
    #pragma unroll
    for (int jj = 0; jj < 12; ++jj) row[sl + jj*4] = ev[jj] * inv;
  }
  __syncthreads();

  #pragma unroll
  for (int i = 0; i < 36; ++i) {
    const int idx = tid + i*256;
    const int o = idx / HD, k2 = idx % HD;
    const float* wrow = Wp + (size_t)o*CC + h*HD;
    float s = 0.f;
    #pragma unroll
    for (int c = 0; c < HD; ++c) s += wrow[c] * att[c][k2];
    Mf[(size_t)b*CC*CC + (size_t)o*CC + h*HD + k2] = s;
  }
}

// W3_b = M_b @ Wv (bf16 out), b3_b = M_b @ bv + bp (fp32).
__global__ __launch_bounds__(192) void w3_kernel(
    const float* __restrict__ Mf, const float* __restrict__ Wkv,
    const float* __restrict__ bkv, const float* __restrict__ bp,
    unsigned short* __restrict__ W3b, float* __restrict__ b3)
{
  const int b  = blockIdx.x;
  const int o0 = blockIdx.y * 8;
  const int j  = threadIdx.x;
  const float* M  = Mf + ((size_t)b*CC + o0)*CC;
  const float* Wv = Wkv + (size_t)CC*CC;
  const float* bv = bkv + CC;

  float acc[8]  = {0.f,0.f,0.f,0.f,0.f,0.f,0.f,0.f};
  float bacc[8] = {0.f,0.f,0.f,0.f,0.f,0.f,0.f,0.f};
  #pragma unroll 4
  for (int k = 0; k < CC; ++k) {
    const float w  = Wv[(size_t)k*CC + j];
    const float bk = bv[k];
    #pragma unroll
    for (int r = 0; r < 8; ++r) {
      const float m = M[r*CC + k];
      acc[r]  += m * w;
      bacc[r] += m * bk;
    }
  }
  unsigned short* dst = W3b + ((size_t)b*CC + o0)*CC + j;
  #pragma unroll
  for (int r = 0; r < 8; ++r) dst[(size_t)r*CC] = f2bf(acc[r]);
  if (j < 8) b3[(size_t)b*CC + o0 + j] = bacc[j] + bp[o0 + j];
}

extern "C" void kernel_launch(void* const* d_in, const int* in_sizes, int n_in,
                              void* d_out, int out_size, void* d_ws, size_t ws_size,
                              hipStream_t stream)
{
  (void)in_sizes; (void)n_in; (void)out_size; (void)ws_size;
  const float* x_q  = (const float*)d_in[0];
  const float* x_k  = (const float*)d_in[1];
  const float* Wq   = (const float*)d_in[2];
  const float* bq   = (const float*)d_in[3];
  const float* Wkv  = (const float*)d_in[4];
  const float* bkv  = (const float*)d_in[5];
  const float* Wp   = (const float*)d_in[6];
  const float* bp   = (const float*)d_in[7];
  const float* temp = (const float*)d_in[8];

  char* p = (char*)d_ws;
  float* gpart = (float*)p;                 p += (size_t)BB*NHD*64*2304*sizeof(float);
  float* mf = (float*)p;                    p += (size_t)BB*CC*CC*sizeof(float);
  unsigned short* w3b = (unsigned short*)p; p += (size_t)BB*CC*CC*sizeof(unsigned short);
  float* b3 = (float*)p;                    p += (size_t)BB*CC*sizeof(float);
  unsigned short* wb = (unsigned short*)p;  // 2*CC*CC bf16 (Wq | Wk)

  cast_w_kernel<<<dim3((2*CC*CC)/256), 256, 0, stream>>>(Wq, Wkv, wb);

  // fused q-proj + k-proj + gram (depth-2 load pipeline)
  qkg_kernel<<<dim3(HW/256, BB), 256, 0, stream>>>(
      x_q, x_k, wb, bq, bkv, gpart);

  attn_m_kernel<<<dim3(BB*NHD), 256, 0, stream>>>(gpart, Wp, temp, mf);
  w3_kernel<<<dim3(BB, 24), 192, 0, stream>>>(mf, Wkv, bkv, bp, w3b, b3);

  // final: out = W3_b @ x_k + b3_b
  proj_fin<<<dim3(HW/256, BB), 256, 0, stream>>>(x_k, w3b, b3, (float*)d_out);
}

// Round 15
// 177.729 us; speedup vs baseline: 1.5403x; 1.0805x over previous
//
#include <hip/hip_runtime.h>
#include <hip/hip_bf16.h>

#define HW 16384
#define CC 192
#define BB 8
#define NHD 4
#define HD 48

typedef __attribute__((ext_vector_type(8))) short  short8;
typedef __attribute__((ext_vector_type(4))) float  f32x4;
typedef __attribute__((ext_vector_type(4))) unsigned short us4;
typedef __attribute__((ext_vector_type(2))) unsigned u32x2;

static __device__ __forceinline__ unsigned short f2bf(float f) {
  unsigned u = __float_as_uint(f);
  u += 0x7fffu + ((u >> 16) & 1u);          // round-to-nearest-even
  return (unsigned short)(u >> 16);
}
// two fp32 -> packed bf16x2 (compiler emits v_cvt_pk_bf16_f32)
static __device__ __forceinline__ unsigned pk2bf(float lo, float hi) {
  __hip_bfloat162 h = __float22bfloat162_rn(make_float2(lo, hi));
  return *reinterpret_cast<unsigned*>(&h);
}

// lgkm-only barrier: LDS visibility without draining vmcnt (T4).
static __device__ __forceinline__ void ldsbar() {
  asm volatile("" ::: "memory");
  asm volatile("s_waitcnt lgkmcnt(0)" ::: "memory");
  __builtin_amdgcn_s_barrier();
  asm volatile("" ::: "memory");
}

// XOR swizzle for staging buffers (row stride 100 dwords): spreads each
// 4-store group over 32 banks (verified R10: conflicts 7.1M -> 2.4M).
#define SWZ_COL(row, cdw) ((cdw) ^ ((((row) >> 3) & 3) << 2))

// Cast Wq (192x192) and Wk (= Wkv rows 0..191) fp32 -> bf16, contiguous.
__global__ __launch_bounds__(256) void cast_w_kernel(
    const float* __restrict__ Wq, const float* __restrict__ Wkv,
    unsigned short* __restrict__ Wb)
{
  const int i = blockIdx.x * 256 + threadIdx.x;   // 0 .. 2*CC*CC-1
  const float v = (i < CC*CC) ? Wq[i] : Wkv[i - CC*CC];
  Wb[i] = f2bf(v);
}

// ---------------------------------------------------------------------------
// Fused q-proj + k-proj + gram (EXACT R10 structure + xkb side-stream).
// Per block: 256 positions (4 tiles of 64), wave = head. qn/kn live only in
// LDS; gram partials accumulated in regs across tiles, written once.
// NEW: during k staging, the already-bf16-packed x_k values are streamed to
// global xkb (background stores; ldsbar does not drain vmcnt) so proj_fin
// can read bf16 (half the bytes).
// ---------------------------------------------------------------------------
__global__ __launch_bounds__(256, 2) void qkg_kernel(
    const float* __restrict__ x_q, const float* __restrict__ x_k,
    const unsigned short* __restrict__ wb,   // [2][CC][CC] bf16 (Wq | Wk)
    const float* __restrict__ bq, const float* __restrict__ bkv,
    float* __restrict__ gpart,
    unsigned short* __restrict__ xkb)        // [CC][HW] bf16 per batch
{
  const int tid  = threadIdx.x;
  const int lane = tid & 63;
  const int wv   = tid >> 6;          // wave = head
  const int b    = blockIdx.y;
  const int p0   = blockIdx.x * 256;
  const int l15  = lane & 15;
  const int lg   = lane >> 4;
  const int qd   = tid & 15;

  __shared__ unsigned short Xs[64][200];      // 25.6 KB, swizzled staging
  __shared__ unsigned short QN[NHD][48][68];  // 26.1 KB
  __shared__ unsigned short KN[NHD][48][68];  // 26.1 KB

  const float* Xq = x_q + (size_t)b*CC*HW;
  const float* Xk = x_k + (size_t)b*CC*HW;
  unsigned short* Xkb = xkb + (size_t)b*CC*HW;

  f32x4 pre[12];
  auto LOADT = [&](const float* X, int pb) {
    #pragma unroll
    for (int i = 0; i < 6; ++i) {
      const int cp = (tid >> 4) + i*16;
      const float* base = X + (size_t)(2*cp)*HW + pb + qd*4;
      pre[2*i]   = *(const f32x4*)(base);
      pre[2*i+1] = *(const f32x4*)(base + HW);
    }
  };
  auto WRITET = [&]() {
    #pragma unroll
    for (int i = 0; i < 6; ++i) {
      const int cp = (tid >> 4) + i*16;
      #pragma unroll
      for (int j = 0; j < 4; ++j) {
        const int row = qd*4 + j;
        *(unsigned*)&Xs[row][2*SWZ_COL(row, cp)] =
            pk2bf(pre[2*i][j], pre[2*i+1][j]);
      }
    }
  };
  // stream the k tile (currently in pre) to global xkb as bf16, coalesced:
  // channel c, positions pb+qd*4 .. +3 -> one 8B store per channel.
  auto WRITEXKB = [&](int pb) {
    #pragma unroll
    for (int i = 0; i < 6; ++i) {
      const int cp = (tid >> 4) + i*16;
      u32x2 a, c2;
      a[0]  = pk2bf(pre[2*i][0],   pre[2*i][1]);
      a[1]  = pk2bf(pre[2*i][2],   pre[2*i][3]);
      c2[0] = pk2bf(pre[2*i+1][0], pre[2*i+1][1]);
      c2[1] = pk2bf(pre[2*i+1][2], pre[2*i+1][3]);
      *(u32x2*)(Xkb + (size_t)(2*cp  )*HW + pb + qd*4) = a;
      *(u32x2*)(Xkb + (size_t)(2*cp+1)*HW + pb + qd*4) = c2;
    }
  };

  // Projection + bias + l2norm; result -> DST[c_local][p_local] (bf16).
  auto PROJ = [&](const unsigned short* W, const float* bias,
                  unsigned short (*DST)[68]) {
    f32x4 acc[3][4];
    #pragma unroll
    for (int mt = 0; mt < 3; ++mt)
      #pragma unroll
      for (int nt = 0; nt < 4; ++nt)
        acc[mt][nt] = (f32x4){0.f, 0.f, 0.f, 0.f};

    #pragma unroll
    for (int kk = 0; kk < 6; ++kk) {
      short8 afr[3], bfr[4];
      #pragma unroll
      for (int mt = 0; mt < 3; ++mt)
        afr[mt] = *(const short8*)(W + (size_t)(wv*48 + mt*16 + l15)*CC + kk*32 + lg*8);
      #pragma unroll
      for (int nt = 0; nt < 4; ++nt) {
        const int lgs = lg ^ ((2*nt + (l15 >> 3)) & 3);   // read-side swizzle
        bfr[nt] = *(const short8*)&Xs[nt*16 + l15][kk*32 + lgs*8];
      }
      #pragma unroll
      for (int mt = 0; mt < 3; ++mt)
        #pragma unroll
        for (int nt = 0; nt < 4; ++nt)
          acc[mt][nt] = __builtin_amdgcn_mfma_f32_16x16x32_bf16(
              afr[mt], bfr[nt], acc[mt][nt], 0, 0, 0);
    }

    #pragma unroll
    for (int nt = 0; nt < 4; ++nt) {
      float v[3][4];
      float ss = 0.f;
      #pragma unroll
      for (int mt = 0; mt < 3; ++mt)
        #pragma unroll
        for (int r = 0; r < 4; ++r) {
          const float x = acc[mt][nt][r] + bias[wv*48 + mt*16 + lg*4 + r];
          v[mt][r] = x;
          ss += x*x;
        }
      ss += __shfl_xor(ss, 16);
      ss += __shfl_xor(ss, 32);
      const float rn = 1.0f / fmaxf(sqrtf(ss), 1e-12f);
      #pragma unroll
      for (int mt = 0; mt < 3; ++mt)
        #pragma unroll
        for (int r = 0; r < 4; ++r)
          DST[mt*16 + lg*4 + r][nt*16 + l15] = f2bf(v[mt][r] * rn);
    }
  };

  f32x4 gacc[3][3];
  #pragma unroll
  for (int mt = 0; mt < 3; ++mt)
    #pragma unroll
    for (int nt = 0; nt < 3; ++nt)
      gacc[mt][nt] = (f32x4){0.f, 0.f, 0.f, 0.f};

  LOADT(Xq, p0);
  for (int t = 0; t < 4; ++t) {
    const int pb = p0 + t*64;
    WRITET();                          // q tile -> Xs (swizzled)
    ldsbar();
    LOADT(Xk, pb);                     // k loads in flight during q compute
    PROJ(wb, bq, QN[wv]);              // q: MFMA + norm -> QN
    ldsbar();                          // all waves done reading Xs(q)
    WRITET();                          // k tile -> Xs
    WRITEXKB(pb);                      // bf16 k tile -> global (background)
    ldsbar();
    if (t < 3) LOADT(Xq, pb + 64);     // next q in flight during k compute
    PROJ(wb + (size_t)CC*CC, bkv, KN[wv]);  // k: MFMA + norm -> KN
    ldsbar();                          // (uniform barrier count across waves)

    // gram: wave-private (own head's QN/KN only) -> no barrier needed
    #pragma unroll
    for (int s = 0; s < 2; ++s) {
      short8 ga[3], gb[3];
      #pragma unroll
      for (int mt = 0; mt < 3; ++mt)
        ga[mt] = *(const short8*)&QN[wv][mt*16 + l15][s*32 + lg*8];
      #pragma unroll
      for (int nt = 0; nt < 3; ++nt)
        gb[nt] = *(const short8*)&KN[wv][nt*16 + l15][s*32 + lg*8];
      #pragma unroll
      for (int mt = 0; mt < 3; ++mt)
        #pragma unroll
        for (int nt = 0; nt < 3; ++nt)
          gacc[mt][nt] = __builtin_amdgcn_mfma_f32_16x16x32_bf16(
              ga[mt], gb[nt], gacc[mt][nt], 0, 0, 0);
    }
  }

  // write 48x48 gram partial for (b, head=wv), slot = blockIdx.x (0..63)
  float* G = gpart + ((size_t)(b*NHD + wv)*64 + blockIdx.x)*2304;
  #pragma unroll
  for (int mt = 0; mt < 3; ++mt)
    #pragma unroll
    for (int nt = 0; nt < 3; ++nt)
      #pragma unroll
      for (int r = 0; r < 4; ++r)
        G[(mt*16 + lg*4 + r)*HD + nt*16 + l15] = gacc[mt][nt][r];
}

// Final projection: out = W3_b @ xkb + b3_b. Reads bf16 (half the bytes of
// R10's fp32 path); pipelined, dbuf, lgkm barriers, swizzled staging.
__global__ __launch_bounds__(256) void proj_fin(
    const unsigned short* __restrict__ xkb,
    const unsigned short* __restrict__ w3b,
    const float* __restrict__ b3,
    float* __restrict__ of)
{
  const int tid  = threadIdx.x;
  const int lane = tid & 63;
  const int wv   = tid >> 6;
  const int b    = blockIdx.y;
  const int p0   = blockIdx.x * 256;
  const int l15  = lane & 15;
  const int lg   = lane >> 4;
  const int qd   = tid & 15;

  __shared__ unsigned short Xt[2][64][200];

  const unsigned short* X = xkb + (size_t)b*CC*HW;
  const unsigned short* Wb = w3b + (size_t)b*CC*CC;
  const float* bias = b3 + (size_t)b*CC;

  short8 afr[6][3];
  #pragma unroll
  for (int kk = 0; kk < 6; ++kk)
    #pragma unroll
    for (int mt = 0; mt < 3; ++mt)
      afr[kk][mt] = *(const short8*)(Wb + (size_t)(wv*48 + mt*16 + l15)*CC + kk*32 + lg*8);

  float bv[3][4];
  #pragma unroll
  for (int mt = 0; mt < 3; ++mt)
    #pragma unroll
    for (int r = 0; r < 4; ++r)
      bv[mt][r] = bias[wv*48 + mt*16 + lg*4 + r];

  us4 pre[12];                        // 12 x 8B bf16 loads
  auto LOADT = [&](int pb) {
    #pragma unroll
    for (int i = 0; i < 6; ++i) {
      const int cp = (tid >> 4) + i*16;
      const unsigned short* base = X + (size_t)(2*cp)*HW + pb + qd*4;
      pre[2*i]   = *(const us4*)(base);
      pre[2*i+1] = *(const us4*)(base + HW);
    }
  };
  auto WRITET = [&](int buf) {
    #pragma unroll
    for (int i = 0; i < 6; ++i) {
      const int cp = (tid >> 4) + i*16;
      #pragma unroll
      for (int j = 0; j < 4; ++j) {
        const int row = qd*4 + j;
        *(unsigned*)&Xt[buf][row][2*SWZ_COL(row, cp)] =
            (unsigned)pre[2*i][j] | ((unsigned)pre[2*i+1][j] << 16);
      }
    }
  };

  float* Ofp = of + (size_t)b*CC*HW;

  auto COMPUTE = [&](int buf, int pb) {
    f32x4 acc[3][4];
    #pragma unroll
    for (int mt = 0; mt < 3; ++mt)
      #pragma unroll
      for (int nt = 0; nt < 4; ++nt)
        acc[mt][nt] = (f32x4){0.f, 0.f, 0.f, 0.f};

    #pragma unroll
    for (int kk = 0; kk < 6; ++kk) {
      short8 bfr[4];
      #pragma unroll
      for (int nt = 0; nt < 4; ++nt) {
        const int lgs = lg ^ ((2*nt + (l15 >> 3)) & 3);   // read-side swizzle
        bfr[nt] = *(const short8*)&Xt[buf][nt*16 + l15][kk*32 + lgs*8];
      }
      #pragma unroll
      for (int mt = 0; mt < 3; ++mt)
        #pragma unroll
        for (int nt = 0; nt < 4; ++nt)
          acc[mt][nt] = __builtin_amdgcn_mfma_f32_16x16x32_bf16(
              afr[kk][mt], bfr[nt], acc[mt][nt], 0, 0, 0);
    }

    #pragma unroll
    for (int nt = 0; nt < 4; ++nt) {
      const int col = pb + nt*16 + l15;
      #pragma unroll
      for (int mt = 0; mt < 3; ++mt)
        #pragma unroll
        for (int r = 0; r < 4; ++r)
          Ofp[(size_t)(wv*48 + mt*16 + lg*4 + r)*HW + col] = acc[mt][nt][r] + bv[mt][r];
    }
  };

  LOADT(p0);
  WRITET(0);
  ldsbar();
  #pragma unroll
  for (int t = 0; t < 4; ++t) {
    if (t < 3) LOADT(p0 + (t+1)*64);
    COMPUTE(t & 1, p0 + t*64);
    if (t < 3) {
      WRITET((t & 1) ^ 1);
      ldsbar();
    }
  }
}

// Per (b,h): reduce 64 gram partials, wave-parallel row softmax, then
// M[b][o][h*48+k] = sum_c Wp[o][h*48+c] * attn[c][k]  (fp32 out).
__global__ __launch_bounds__(256) void attn_m_kernel(
    const float* __restrict__ Gpart,
    const float* __restrict__ Wp,
    const float* __restrict__ temp,
    float* __restrict__ Mf)
{
  __shared__ float att[HD][52];
  const int bh  = blockIdx.x;          // 0..31
  const int b   = bh >> 2, h = bh & 3;
  const int tid = threadIdx.x;
  const float* src = Gpart + (size_t)bh*64*2304;

  #pragma unroll
  for (int i = 0; i < 9; ++i) {
    const int e = tid + i*256;         // 2304 = 9*256
    float s = 0.f;
    #pragma unroll
    for (int k = 0; k < 64; ++k) s += src[(size_t)k*2304 + e];
    att[e/48][e%48] = s;
  }
  __syncthreads();

  const int g = tid >> 2, sl = tid & 3;
  if (g < HD) {
    const float t = temp[h];
    const float scale = 0.1f / (1.0f + expf(-t));   // 0.1*sigmoid(t)
    float* row = att[g];
    float m = -1e30f;
    #pragma unroll
    for (int jj = 0; jj < 12; ++jj) m = fmaxf(m, row[sl + jj*4]);
    m = fmaxf(m, __shfl_xor(m, 1));
    m = fmaxf(m, __shfl_xor(m, 2));
    float ev[12];
    float s = 0.f;
    #pragma unroll
    for (int jj = 0; jj < 12; ++jj) {
      const float e = expf((row[sl + jj*4] - m) * scale);
      ev[jj] = e; s += e;
    }
    s += __shfl_xor(s, 1);
    s += __shfl_xor(s, 2);
    const float inv = 1.0f / s;
    #pragma unroll
    for (int jj = 0; jj < 12; ++jj) row[sl + jj*4] = ev[jj] * inv;
  }
  __syncthreads();

  #pragma unroll
  for (int i = 0; i < 36; ++i) {
    const int idx = tid + i*256;
    const int o = idx / HD, k2 = idx % HD;
    const float* wrow = Wp + (size_t)o*CC + h*HD;
    float s = 0.f;
    #pragma unroll
    for (int c = 0; c < HD; ++c) s += wrow[c] * att[c][k2];
    Mf[(size_t)b*CC*CC + (size_t)o*CC + h*HD + k2] = s;
  }
}

// W3_b = M_b @ Wv (bf16 out), b3_b = M_b @ bv + bp (fp32).
__global__ __launch_bounds__(192) void w3_kernel(
    const float* __restrict__ Mf, const float* __restrict__ Wkv,
    const float* __restrict__ bkv, const float* __restrict__ bp,
    unsigned short* __restrict__ W3b, float* __restrict__ b3)
{
  const int b  = blockIdx.x;
  const int o0 = blockIdx.y * 8;
  const int j  = threadIdx.x;
  const float* M  = Mf + ((size_t)b*CC + o0)*CC;
  const float* Wv = Wkv + (size_t)CC*CC;
  const float* bv = bkv + CC;

  float acc[8]  = {0.f,0.f,0.f,0.f,0.f,0.f,0.f,0.f};
  float bacc[8] = {0.f,0.f,0.f,0.f,0.f,0.f,0.f,0.f};
  #pragma unroll 4
  for (int k = 0; k < CC; ++k) {
    const float w  = Wv[(size_t)k*CC + j];
    const float bk = bv[k];
    #pragma unroll
    for (int r = 0; r < 8; ++r) {
      const float m = M[r*CC + k];
      acc[r]  += m * w;
      bacc[r] += m * bk;
    }
  }
  unsigned short* dst = W3b + ((size_t)b*CC + o0)*CC + j;
  #pragma unroll
  for (int r = 0; r < 8; ++r) dst[(size_t)r*CC] = f2bf(acc[r]);
  if (j < 8) b3[(size_t)b*CC + o0 + j] = bacc[j] + bp[o0 + j];
}

extern "C" void kernel_launch(void* const* d_in, const int* in_sizes, int n_in,
                              void* d_out, int out_size, void* d_ws, size_t ws_size,
                              hipStream_t stream)
{
  (void)in_sizes; (void)n_in; (void)out_size; (void)ws_size;
  const float* x_q  = (const float*)d_in[0];
  const float* x_k  = (const float*)d_in[1];
  const float* Wq   = (const float*)d_in[2];
  const float* bq   = (const float*)d_in[3];
  const float* Wkv  = (const float*)d_in[4];
  const float* bkv  = (const float*)d_in[5];
  const float* Wp   = (const float*)d_in[6];
  const float* bp   = (const float*)d_in[7];
  const float* temp = (const float*)d_in[8];

  char* p = (char*)d_ws;
  float* gpart = (float*)p;                 p += (size_t)BB*NHD*64*2304*sizeof(float);
  float* mf = (float*)p;                    p += (size_t)BB*CC*CC*sizeof(float);
  unsigned short* w3b = (unsigned short*)p; p += (size_t)BB*CC*CC*sizeof(unsigned short);
  float* b3 = (float*)p;                    p += (size_t)BB*CC*sizeof(float);
  unsigned short* wb = (unsigned short*)p;  p += (size_t)2*CC*CC*sizeof(unsigned short);
  unsigned short* xkb = (unsigned short*)p; // BB*CC*HW bf16 (50.3 MB)

  cast_w_kernel<<<dim3((2*CC*CC)/256), 256, 0, stream>>>(Wq, Wkv, wb);

  // fused q-proj + k-proj + gram (+ bf16 x_k side-stream for proj_fin)
  qkg_kernel<<<dim3(HW/256, BB), 256, 0, stream>>>(
      x_q, x_k, wb, bq, bkv, gpart, xkb);

  attn_m_kernel<<<dim3(BB*NHD), 256, 0, stream>>>(gpart, Wp, temp, mf);
  w3_kernel<<<dim3(BB, 24), 192, 0, stream>>>(mf, Wkv, bkv, bp, w3b, b3);

  // final: out = W3_b @ xkb + b3_b  (bf16 reads)
  proj_fin<<<dim3(HW/256, BB), 256, 0, stream>>>(xkb, w3b, b3, (float*)d_out);
}

// Round 16
// 167.585 us; speedup vs baseline: 1.6336x; 1.0605x over previous
//
#include <hip/hip_runtime.h>
#include <hip/hip_bf16.h>

#define HW 16384
#define CC 192
#define BB 8
#define NHD 4
#define HD 48

typedef __attribute__((ext_vector_type(8))) short  short8;
typedef __attribute__((ext_vector_type(4))) float  f32x4;

static __device__ __forceinline__ unsigned short f2bf(float f) {
  unsigned u = __float_as_uint(f);
  u += 0x7fffu + ((u >> 16) & 1u);          // round-to-nearest-even
  return (unsigned short)(u >> 16);
}
// two fp32 -> packed bf16x2 (compiler emits v_cvt_pk_bf16_f32)
static __device__ __forceinline__ unsigned pk2bf(float lo, float hi) {
  __hip_bfloat162 h = __float22bfloat162_rn(make_float2(lo, hi));
  return *reinterpret_cast<unsigned*>(&h);
}

// lgkm-only barrier: LDS visibility without draining vmcnt (T4).
static __device__ __forceinline__ void ldsbar() {
  asm volatile("" ::: "memory");
  asm volatile("s_waitcnt lgkmcnt(0)" ::: "memory");
  __builtin_amdgcn_s_barrier();
  asm volatile("" ::: "memory");
}

// XOR swizzle for the staging buffers (row stride 100 dwords):
// plain writes collapse to 8 banks (row term = 16*(qd&1) only). Injecting
// row bits (row>>3)&3 into column dword bits 2-3 spreads each store over
// 32 banks (2 lanes/bank = free). Involution; b128-aligned (bits 2-3 only).
#define SWZ_COL(row, cdw) ((cdw) ^ ((((row) >> 3) & 3) << 2))

// Cast Wq (192x192) and Wk (= Wkv rows 0..191) fp32 -> bf16, contiguous.
__global__ __launch_bounds__(256) void cast_w_kernel(
    const float* __restrict__ Wq, const float* __restrict__ Wkv,
    unsigned short* __restrict__ Wb)
{
  const int i = blockIdx.x * 256 + threadIdx.x;   // 0 .. 2*CC*CC-1
  const float v = (i < CC*CC) ? Wq[i] : Wkv[i - CC*CC];
  Wb[i] = f2bf(v);
}

// ---------------------------------------------------------------------------
// Fused q-proj + k-proj + gram (R8 structure + Xs XOR swizzle) — best-known
// configuration (R10, 168 µs). Per block: 256 positions (4 tiles of 64),
// wave = head. qn/kn live only in LDS; gram partials accumulated in regs
// across tiles, written once.
// ---------------------------------------------------------------------------
__global__ __launch_bounds__(256, 2) void qkg_kernel(
    const float* __restrict__ x_q, const float* __restrict__ x_k,
    const unsigned short* __restrict__ wb,   // [2][CC][CC] bf16 (Wq | Wk)
    const float* __restrict__ bq, const float* __restrict__ bkv,
    float* __restrict__ gpart)
{
  const int tid  = threadIdx.x;
  const int lane = tid & 63;
  const int wv   = tid >> 6;          // wave = head
  const int b    = blockIdx.y;
  const int p0   = blockIdx.x * 256;
  const int l15  = lane & 15;
  const int lg   = lane >> 4;
  const int qd   = tid & 15;

  __shared__ unsigned short Xs[64][200];      // 25.6 KB, swizzled staging
  __shared__ unsigned short QN[NHD][48][68];  // 26.1 KB
  __shared__ unsigned short KN[NHD][48][68];  // 26.1 KB

  const float* Xq = x_q + (size_t)b*CC*HW;
  const float* Xk = x_k + (size_t)b*CC*HW;

  f32x4 pre[12];
  auto LOADT = [&](const float* X, int pb) {
    #pragma unroll
    for (int i = 0; i < 6; ++i) {
      const int cp = (tid >> 4) + i*16;
      const float* base = X + (size_t)(2*cp)*HW + pb + qd*4;
      pre[2*i]   = *(const f32x4*)(base);
      pre[2*i+1] = *(const f32x4*)(base + HW);
    }
  };
  auto WRITET = [&]() {
    #pragma unroll
    for (int i = 0; i < 6; ++i) {
      const int cp = (tid >> 4) + i*16;
      #pragma unroll
      for (int j = 0; j < 4; ++j) {
        const int row = qd*4 + j;
        *(unsigned*)&Xs[row][2*SWZ_COL(row, cp)] =
            pk2bf(pre[2*i][j], pre[2*i+1][j]);
      }
    }
  };

  // Projection + bias + l2norm; result -> DST[c_local][p_local] (bf16).
  auto PROJ = [&](const unsigned short* W, const float* bias,
                  unsigned short (*DST)[68]) {
    f32x4 acc[3][4];
    #pragma unroll
    for (int mt = 0; mt < 3; ++mt)
      #pragma unroll
      for (int nt = 0; nt < 4; ++nt)
        acc[mt][nt] = (f32x4){0.f, 0.f, 0.f, 0.f};

    #pragma unroll
    for (int kk = 0; kk < 6; ++kk) {
      short8 afr[3], bfr[4];
      #pragma unroll
      for (int mt = 0; mt < 3; ++mt)
        afr[mt] = *(const short8*)(W + (size_t)(wv*48 + mt*16 + l15)*CC + kk*32 + lg*8);
      #pragma unroll
      for (int nt = 0; nt < 4; ++nt) {
        const int lgs = lg ^ ((2*nt + (l15 >> 3)) & 3);   // read-side swizzle
        bfr[nt] = *(const short8*)&Xs[nt*16 + l15][kk*32 + lgs*8];
      }
      #pragma unroll
      for (int mt = 0; mt < 3; ++mt)
        #pragma unroll
        for (int nt = 0; nt < 4; ++nt)
          acc[mt][nt] = __builtin_amdgcn_mfma_f32_16x16x32_bf16(
              afr[mt], bfr[nt], acc[mt][nt], 0, 0, 0);
    }

    #pragma unroll
    for (int nt = 0; nt < 4; ++nt) {
      float v[3][4];
      float ss = 0.f;
      #pragma unroll
      for (int mt = 0; mt < 3; ++mt)
        #pragma unroll
        for (int r = 0; r < 4; ++r) {
          const float x = acc[mt][nt][r] + bias[wv*48 + mt*16 + lg*4 + r];
          v[mt][r] = x;
          ss += x*x;
        }
      ss += __shfl_xor(ss, 16);
      ss += __shfl_xor(ss, 32);
      const float rn = 1.0f / fmaxf(sqrtf(ss), 1e-12f);
      #pragma unroll
      for (int mt = 0; mt < 3; ++mt)
        #pragma unroll
        for (int r = 0; r < 4; ++r)
          DST[mt*16 + lg*4 + r][nt*16 + l15] = f2bf(v[mt][r] * rn);
    }
  };

  f32x4 gacc[3][3];
  #pragma unroll
  for (int mt = 0; mt < 3; ++mt)
    #pragma unroll
    for (int nt = 0; nt < 3; ++nt)
      gacc[mt][nt] = (f32x4){0.f, 0.f, 0.f, 0.f};

  LOADT(Xq, p0);
  for (int t = 0; t < 4; ++t) {
    const int pb = p0 + t*64;
    WRITET();                          // q tile -> Xs (swizzled)
    ldsbar();
    LOADT(Xk, pb);                     // k loads in flight during q compute
    PROJ(wb, bq, QN[wv]);              // q: MFMA + norm -> QN
    ldsbar();                          // all waves done reading Xs(q)
    WRITET();                          // k tile -> Xs
    ldsbar();
    if (t < 3) LOADT(Xq, pb + 64);     // next q in flight during k compute
    PROJ(wb + (size_t)CC*CC, bkv, KN[wv]);  // k: MFMA + norm -> KN
    ldsbar();                          // (uniform barrier count across waves)

    // gram: wave-private (own head's QN/KN only) -> no barrier needed
    #pragma unroll
    for (int s = 0; s < 2; ++s) {
      short8 ga[3], gb[3];
      #pragma unroll
      for (int mt = 0; mt < 3; ++mt)
        ga[mt] = *(const short8*)&QN[wv][mt*16 + l15][s*32 + lg*8];
      #pragma unroll
      for (int nt = 0; nt < 3; ++nt)
        gb[nt] = *(const short8*)&KN[wv][nt*16 + l15][s*32 + lg*8];
      #pragma unroll
      for (int mt = 0; mt < 3; ++mt)
        #pragma unroll
        for (int nt = 0; nt < 3; ++nt)
          gacc[mt][nt] = __builtin_amdgcn_mfma_f32_16x16x32_bf16(
              ga[mt], gb[nt], gacc[mt][nt], 0, 0, 0);
    }
  }

  // write 48x48 gram partial for (b, head=wv), slot = blockIdx.x (0..63)
  float* G = gpart + ((size_t)(b*NHD + wv)*64 + blockIdx.x)*2304;
  #pragma unroll
  for (int mt = 0; mt < 3; ++mt)
    #pragma unroll
    for (int nt = 0; nt < 3; ++nt)
      #pragma unroll
      for (int r = 0; r < 4; ++r)
        G[(mt*16 + lg*4 + r)*HD + nt*16 + l15] = gacc[mt][nt][r];
}

// Final projection: out = W3_b @ x_k + b3_b (pipelined, dbuf, lgkm barriers,
// swizzled staging).
__global__ __launch_bounds__(256) void proj_fin(
    const float* __restrict__ x_k,
    const unsigned short* __restrict__ w3b,
    const float* __restrict__ b3,
    float* __restrict__ of)
{
  const int tid  = threadIdx.x;
  const int lane = tid & 63;
  const int wv   = tid >> 6;
  const int b    = blockIdx.y;
  const int p0   = blockIdx.x * 256;
  const int l15  = lane & 15;
  const int lg   = lane >> 4;
  const int qd   = tid & 15;

  __shared__ unsigned short Xt[2][64][200];

  const float* X = x_k + (size_t)b*CC*HW;
  const unsigned short* Wb = w3b + (size_t)b*CC*CC;
  const float* bias = b3 + (size_t)b*CC;

  short8 afr[6][3];
  #pragma unroll
  for (int kk = 0; kk < 6; ++kk)
    #pragma unroll
    for (int mt = 0; mt < 3; ++mt)
      afr[kk][mt] = *(const short8*)(Wb + (size_t)(wv*48 + mt*16 + l15)*CC + kk*32 + lg*8);

  float bv[3][4];
  #pragma unroll
  for (int mt = 0; mt < 3; ++mt)
    #pragma unroll
    for (int r = 0; r < 4; ++r)
      bv[mt][r] = bias[wv*48 + mt*16 + lg*4 + r];

  f32x4 pre[12];
  auto LOADT = [&](int pb) {
    #pragma unroll
    for (int i = 0; i < 6; ++i) {
      const int cp = (tid >> 4) + i*16;
      const float* base = X + (size_t)(2*cp)*HW + pb + qd*4;
      pre[2*i]   = *(const f32x4*)(base);
      pre[2*i+1] = *(const f32x4*)(base + HW);
    }
  };
  auto WRITET = [&](int buf) {
    #pragma unroll
    for (int i = 0; i < 6; ++i) {
      const int cp = (tid >> 4) + i*16;
      #pragma unroll
      for (int j = 0; j < 4; ++j) {
        const int row = qd*4 + j;
        *(unsigned*)&Xt[buf][row][2*SWZ_COL(row, cp)] =
            pk2bf(pre[2*i][j], pre[2*i+1][j]);
      }
    }
  };

  float* Ofp = of + (size_t)b*CC*HW;

  auto COMPUTE = [&](int buf, int pb) {
    f32x4 acc[3][4];
    #pragma unroll
    for (int mt = 0; mt < 3; ++mt)
      #pragma unroll
      for (int nt = 0; nt < 4; ++nt)
        acc[mt][nt] = (f32x4){0.f, 0.f, 0.f, 0.f};

    #pragma unroll
    for (int kk = 0; kk < 6; ++kk) {
      short8 bfr[4];
      #pragma unroll
      for (int nt = 0; nt < 4; ++nt) {
        const int lgs = lg ^ ((2*nt + (l15 >> 3)) & 3);   // read-side swizzle
        bfr[nt] = *(const short8*)&Xt[buf][nt*16 + l15][kk*32 + lgs*8];
      }
      #pragma unroll
      for (int mt = 0; mt < 3; ++mt)
        #pragma unroll
        for (int nt = 0; nt < 4; ++nt)
          acc[mt][nt] = __builtin_amdgcn_mfma_f32_16x16x32_bf16(
              afr[kk][mt], bfr[nt], acc[mt][nt], 0, 0, 0);
    }

    #pragma unroll
    for (int nt = 0; nt < 4; ++nt) {
      const int col = pb + nt*16 + l15;
      #pragma unroll
      for (int mt = 0; mt < 3; ++mt)
        #pragma unroll
        for (int r = 0; r < 4; ++r)
          Ofp[(size_t)(wv*48 + mt*16 + lg*4 + r)*HW + col] = acc[mt][nt][r] + bv[mt][r];
    }
  };

  LOADT(p0);
  WRITET(0);
  ldsbar();
  #pragma unroll
  for (int t = 0; t < 4; ++t) {
    if (t < 3) LOADT(p0 + (t+1)*64);
    COMPUTE(t & 1, p0 + t*64);
    if (t < 3) {
      WRITET((t & 1) ^ 1);
      ldsbar();
    }
  }
}

// Per (b,h): reduce 64 gram partials, wave-parallel row softmax, then
// M[b][o][h*48+k] = sum_c Wp[o][h*48+c] * attn[c][k]  (fp32 out).
__global__ __launch_bounds__(256) void attn_m_kernel(
    const float* __restrict__ Gpart,
    const float* __restrict__ Wp,
    const float* __restrict__ temp,
    float* __restrict__ Mf)
{
  __shared__ float att[HD][52];
  const int bh  = blockIdx.x;          // 0..31
  const int b   = bh >> 2, h = bh & 3;
  const int tid = threadIdx.x;
  const float* src = Gpart + (size_t)bh*64*2304;

  #pragma unroll
  for (int i = 0; i < 9; ++i) {
    const int e = tid + i*256;         // 2304 = 9*256
    float s = 0.f;
    #pragma unroll
    for (int k = 0; k < 64; ++k) s += src[(size_t)k*2304 + e];
    att[e/48][e%48] = s;
  }
  __syncthreads();

  const int g = tid >> 2, sl = tid & 3;
  if (g < HD) {
    const float t = temp[h];
    const float scale = 0.1f / (1.0f + expf(-t));   // 0.1*sigmoid(t)
    float* row = att[g];
    float m = -1e30f;
    #pragma unroll
    for (int jj = 0; jj < 12; ++jj) m = fmaxf(m, row[sl + jj*4]);
    m = fmaxf(m, __shfl_xor(m, 1));
    m = fmaxf(m, __shfl_xor(m, 2));
    float ev[12];
    float s = 0.f;
    #pragma unroll
    for (int jj = 0; jj < 12; ++jj) {
      const float e = expf((row[sl + jj*4] - m) * scale);
      ev[jj] = e; s += e;
    }
    s += __shfl_xor(s, 1);
    s += __shfl_xor(s, 2);
    const float inv = 1.0f / s;
    #pragma unroll
    for (int jj = 0; jj < 12; ++jj) row[sl + jj*4] = ev[jj] * inv;
  }
  __syncthreads();

  #pragma unroll
  for (int i = 0; i < 36; ++i) {
    const int idx = tid + i*256;
    const int o = idx / HD, k2 = idx % HD;
    const float* wrow = Wp + (size_t)o*CC + h*HD;
    float s = 0.f;
    #pragma unroll
    for (int c = 0; c < HD; ++c) s += wrow[c] * att[c][k2];
    Mf[(size_t)b*CC*CC + (size_t)o*CC + h*HD + k2] = s;
  }
}

// W3_b = M_b @ Wv (bf16 out), b3_b = M_b @ bv + bp (fp32).
__global__ __launch_bounds__(192) void w3_kernel(
    const float* __restrict__ Mf, const float* __restrict__ Wkv,
    const float* __restrict__ bkv, const float* __restrict__ bp,
    unsigned short* __restrict__ W3b, float* __restrict__ b3)
{
  const int b  = blockIdx.x;
  const int o0 = blockIdx.y * 8;
  const int j  = threadIdx.x;
  const float* M  = Mf + ((size_t)b*CC + o0)*CC;
  const float* Wv = Wkv + (size_t)CC*CC;
  const float* bv = bkv + CC;

  float acc[8]  = {0.f,0.f,0.f,0.f,0.f,0.f,0.f,0.f};
  float bacc[8] = {0.f,0.f,0.f,0.f,0.f,0.f,0.f,0.f};
  #pragma unroll 4
  for (int k = 0; k < CC; ++k) {
    const float w  = Wv[(size_t)k*CC + j];
    const float bk = bv[k];
    #pragma unroll
    for (int r = 0; r < 8; ++r) {
      const float m = M[r*CC + k];
      acc[r]  += m * w;
      bacc[r] += m * bk;
    }
  }
  unsigned short* dst = W3b + ((size_t)b*CC + o0)*CC + j;
  #pragma unroll
  for (int r = 0; r < 8; ++r) dst[(size_t)r*CC] = f2bf(acc[r]);
  if (j < 8) b3[(size_t)b*CC + o0 + j] = bacc[j] + bp[o0 + j];
}

extern "C" void kernel_launch(void* const* d_in, const int* in_sizes, int n_in,
                              void* d_out, int out_size, void* d_ws, size_t ws_size,
                              hipStream_t stream)
{
  (void)in_sizes; (void)n_in; (void)out_size; (void)ws_size;
  const float* x_q  = (const float*)d_in[0];
  const float* x_k  = (const float*)d_in[1];
  const float* Wq   = (const float*)d_in[2];
  const float* bq   = (const float*)d_in[3];
  const float* Wkv  = (const float*)d_in[4];
  const float* bkv  = (const float*)d_in[5];
  const float* Wp   = (const float*)d_in[6];
  const float* bp   = (const float*)d_in[7];
  const float* temp = (const float*)d_in[8];

  char* p = (char*)d_ws;
  float* gpart = (float*)p;                 p += (size_t)BB*NHD*64*2304*sizeof(float);
  float* mf = (float*)p;                    p += (size_t)BB*CC*CC*sizeof(float);
  unsigned short* w3b = (unsigned short*)p; p += (size_t)BB*CC*CC*sizeof(unsigned short);
  float* b3 = (float*)p;                    p += (size_t)BB*CC*sizeof(float);
  unsigned short* wb = (unsigned short*)p;  // 2*CC*CC bf16 (Wq | Wk)

  cast_w_kernel<<<dim3((2*CC*CC)/256), 256, 0, stream>>>(Wq, Wkv, wb);

  // fused q-proj + k-proj + gram (qn/kn stay in LDS)
  qkg_kernel<<<dim3(HW/256, BB), 256, 0, stream>>>(
      x_q, x_k, wb, bq, bkv, gpart);

  attn_m_kernel<<<dim3(BB*NHD), 256, 0, stream>>>(gpart, Wp, temp, mf);
  w3_kernel<<<dim3(BB, 24), 192, 0, stream>>>(mf, Wkv, bkv, bp, w3b, b3);

  // final: out = W3_b @ x_k + b3_b
  proj_fin<<<dim3(HW/256, BB), 256, 0, stream>>>(x_k, w3b, b3, (float*)d_out);
}